// Round 2
// baseline (50.644 us; speedup 1.0000x reference)
//
#include <hip/hip_runtime.h>

// YOLOv1 loss: pred (N,7,7,30) fp32, target (N,7,7,25) fp32 -> scalar fp32.
// Round 2: LDS-staged, fully-coalesced float4 global loads (round 1 was
// request-bound: strided per-cell loads thrashed L1, 1.5 TB/s HBM).
// Two-pass deterministic reduce.

#define SS 7
#define NCLS 20
#define PRED_C 30
#define TGT_C  25
#define CHUNK 256                      // cells per block
#define PRED_F4 (CHUNK * PRED_C / 4)   // 1920 float4 = 30720 B
#define TGT_F4  (CHUNK * TGT_C  / 4)   // 1600 float4 = 25600 B

__device__ __forceinline__ float block_reduce(float acc) {
    #pragma unroll
    for (int off = 32; off; off >>= 1) acc += __shfl_down(acc, off, 64);
    __shared__ float smem[4];
    int lane = threadIdx.x & 63, wid = threadIdx.x >> 6;
    if (lane == 0) smem[wid] = acc;
    __syncthreads();
    float s = 0.f;
    if (threadIdx.x == 0) {
        #pragma unroll
        for (int w = 0; w < 4; ++w) s += smem[w];
    }
    return s;
}

__global__ void __launch_bounds__(256)
yolo_loss_partial(const float* __restrict__ pred,
                  const float* __restrict__ target,
                  float* __restrict__ partial,
                  int ncells, int nchunks, float inv_n) {
    __shared__ float lds_pred[CHUNK * PRED_C];  // 30720 B
    __shared__ float lds_tgt[CHUNK * TGT_C];    // 25600 B

    const float LC = 5.0f;
    const float LN = 0.5f;
    const float EPS = 1e-6f;
    const float SQE = 1e-12f;

    float acc = 0.f;

    for (int chunk = blockIdx.x; chunk < nchunks; chunk += gridDim.x) {
        const int base = chunk * CHUNK;

        // ---- stage: coalesced float4 loads -> linear LDS ----
        {
            // pred chunk byte offset = chunk*30720 (16B aligned)
            const float4* gp4 =
                reinterpret_cast<const float4*>(pred) + (size_t)chunk * PRED_F4;
            float4* lp4 = reinterpret_cast<float4*>(lds_pred);
            // total pred float4 count (ncells*30 floats; N even -> /4 exact)
            const long pRemain = ((long)ncells * PRED_C) / 4 - (long)chunk * PRED_F4;
            const int pCnt = pRemain < PRED_F4 ? (int)pRemain : PRED_F4;
            for (int i = threadIdx.x; i < pCnt; i += 256) lp4[i] = gp4[i];

            const float4* gt4 =
                reinterpret_cast<const float4*>(target) + (size_t)chunk * TGT_F4;
            float4* lt4 = reinterpret_cast<float4*>(lds_tgt);
            const long tRemain = ((long)ncells * TGT_C) / 4 - (long)chunk * TGT_F4;
            const int tCnt = tRemain < TGT_F4 ? (int)tRemain : TGT_F4;
            for (int i = threadIdx.x; i < tCnt; i += 256) lt4[i] = gt4[i];
        }
        __syncthreads();

        // ---- compute: thread i owns cell base+i, gathers from LDS ----
        const int cell = base + threadIdx.x;
        if (cell < ncells) {
            const float* pv = lds_pred + threadIdx.x * PRED_C;
            const float* tv = lds_tgt + threadIdx.x * TGT_C;

            float obj = tv[NCLS];

            float cls = 0.f;
            #pragma unroll
            for (int c = 0; c < NCLS; ++c) {
                float d = pv[c] - tv[c];
                cls += d * d;
            }

            float tx = tv[NCLS + 1], ty = tv[NCLS + 2];
            float tw = tv[NCLS + 3], th = tv[NCLS + 4];
            float bx1 = tx - tw * 0.5f, bx2 = tx + tw * 0.5f;
            float by1 = ty - th * 0.5f, by2 = ty + th * 0.5f;
            float tarea = tw * th;

            float c0 = pv[NCLS + 0];
            float x0 = pv[NCLS + 1], y0 = pv[NCLS + 2];
            float w0 = pv[NCLS + 3], h0 = pv[NCLS + 4];
            float a0x1 = x0 - w0 * 0.5f, a0x2 = x0 + w0 * 0.5f;
            float a0y1 = y0 - h0 * 0.5f, a0y2 = y0 + h0 * 0.5f;
            float iw0 = fmaxf(fminf(a0x2, bx2) - fmaxf(a0x1, bx1), 0.f);
            float ih0 = fmaxf(fminf(a0y2, by2) - fmaxf(a0y1, by1), 0.f);
            float in0 = iw0 * ih0;
            float iou0 = in0 / (w0 * h0 + tarea - in0 + EPS);

            float c1 = pv[NCLS + 5];
            float x1 = pv[NCLS + 6], y1 = pv[NCLS + 7];
            float w1 = pv[NCLS + 8], h1 = pv[NCLS + 9];
            float a1x1 = x1 - w1 * 0.5f, a1x2 = x1 + w1 * 0.5f;
            float a1y1 = y1 - h1 * 0.5f, a1y2 = y1 + h1 * 0.5f;
            float iw1 = fmaxf(fminf(a1x2, bx2) - fmaxf(a1x1, bx1), 0.f);
            float ih1 = fmaxf(fminf(a1y2, by2) - fmaxf(a1y1, by1), 0.f);
            float in1 = iw1 * ih1;
            float iou1 = in1 / (w1 * h1 + tarea - in1 + EPS);

            bool b0 = (iou0 >= iou1);                 // first index wins ties
            float best_iou = fmaxf(iou0, iou1);
            float bx = b0 ? x0 : x1;
            float by = b0 ? y0 : y1;
            float bw = b0 ? w0 : w1;
            float bh = b0 ? h0 : h1;
            float bc = b0 ? c0 : c1;

            float dx = bx - tx, dy = by - ty;
            float dw = sqrtf(fmaxf(bw, SQE)) - sqrtf(fmaxf(tw, SQE));
            float dh = sqrtf(fmaxf(bh, SQE)) - sqrtf(fmaxf(th, SQE));
            float coord = LC * (dx * dx + dy * dy + dw * dw + dh * dh);

            float dconf = bc - best_iou;
            float objconf = dconf * dconf;
            float noobj = LN * (c0 * c0 + c1 * c1);

            acc += obj * (cls + coord + objconf) + (1.f - obj) * noobj;
        }
        __syncthreads();   // protect LDS before next chunk's restage
    }

    float s = block_reduce(acc);
    if (threadIdx.x == 0) partial[blockIdx.x] = s * inv_n;
}

__global__ void __launch_bounds__(256)
yolo_reduce(const float* __restrict__ partial, float* __restrict__ out, int n) {
    float acc = 0.f;
    for (int i = threadIdx.x; i < n; i += blockDim.x) acc += partial[i];
    float s = block_reduce(acc);
    if (threadIdx.x == 0) out[0] = s;
}

extern "C" void kernel_launch(void* const* d_in, const int* in_sizes, int n_in,
                              void* d_out, int out_size, void* d_ws, size_t ws_size,
                              hipStream_t stream) {
    const float* pred = (const float*)d_in[0];
    const float* target = (const float*)d_in[1];
    float* out = (float*)d_out;
    float* partial = (float*)d_ws;

    int N = in_sizes[0] / (SS * SS * PRED_C);
    int ncells = N * SS * SS;
    int nchunks = (ncells + CHUNK - 1) / CHUNK;   // 3136 for N=16384

    int nblk = nchunks;
    int wsCap = (int)(ws_size / sizeof(float));
    if (nblk > wsCap) nblk = wsCap;
    if (nblk < 1) nblk = 1;

    yolo_loss_partial<<<nblk, 256, 0, stream>>>(pred, target, partial, ncells,
                                                nchunks, 1.0f / (float)N);
    yolo_reduce<<<1, 256, 0, stream>>>(partial, out, nblk);
}